// Round 10
// baseline (208.557 us; speedup 1.0000x reference)
//
#include <hip/hip_runtime.h>
#include <stdint.h>

typedef unsigned short u16;
typedef __attribute__((ext_vector_type(8))) short bf16x8;
typedef __attribute__((ext_vector_type(4))) float f32x4;
typedef __attribute__((ext_vector_type(4))) unsigned short u16x4;

#define DIM 2048
#define HEADS 16
#define HEAD_DIM 128
#define HALF 64
#define LATENT 256
#define BATCH 2
#define SEQ 2048
#define TOK (BATCH*SEQ)

#if defined(__has_builtin)
#if __has_builtin(__builtin_amdgcn_exp2f)
#define EXP2F(x) __builtin_amdgcn_exp2f(x)
#endif
#endif
#ifndef EXP2F
#define EXP2F(x) exp2f(x)
#endif

#define SCALE_C 0.18033688011112042f   // (1/sqrt(64)) * log2(e), folded into Q

__device__ __forceinline__ u16 f2bf(float f) {
  uint32_t u = __float_as_uint(f);
  u += 0x7fff + ((u >> 16) & 1);   // round-to-nearest-even
  return (u16)(u >> 16);
}

__device__ __forceinline__ f32x4 mfma16(bf16x8 a, bf16x8 b, f32x4 c) {
  return __builtin_amdgcn_mfma_f32_16x16x32_bf16(a, b, c, 0, 0, 0);
}

__device__ __forceinline__ void async_copy16(const void* g, void* l) {
  __builtin_amdgcn_global_load_lds(
      (const __attribute__((address_space(1))) void*)g,
      (__attribute__((address_space(3))) void*)l, 16, 0, 0);
}

// ---------------- fp32 -> bf16 elementwise ----------------
__global__ void conv_f32_bf16_k(const float* __restrict__ in, u16* __restrict__ out, int n4) {
  int t = blockIdx.x * 256 + threadIdx.x;
  if (t >= n4) return;
  float4 v = ((const float4*)in)[t];
  u16x4 o = { f2bf(v.x), f2bf(v.y), f2bf(v.z), f2bf(v.w) };
  *(u16x4*)(out + (size_t)t * 4) = o;
}

// ---------------- transpose fp32[K][N] -> bf16[N][K], z selects src/dst ----------------
__global__ void transpose_w_k(const float* __restrict__ in0, const float* __restrict__ in1,
                              u16* __restrict__ out0, u16* __restrict__ out1,
                              int N, int row_step, int out_ld) {
  __shared__ float tile[32][33];
  const float* in = blockIdx.z ? in1 : in0;
  u16* out = blockIdx.z ? out1 : out0;
  int row_off = blockIdx.z * row_step;
  int k0 = blockIdx.y * 32, n0 = blockIdx.x * 32;
  int tx = threadIdx.x, ty = threadIdx.y;
  #pragma unroll
  for (int j = 0; j < 32; j += 8)
    tile[ty + j][tx] = in[(size_t)(k0 + ty + j) * N + n0 + tx];
  __syncthreads();
  #pragma unroll
  for (int j = 0; j < 32; j += 8)
    out[(size_t)(n0 + ty + j + row_off) * out_ld + k0 + tx] = f2bf(tile[tx][ty + j]);
}

// ---------------- transpose bf16 v[b*S+s][c] -> vT[b][c][p(s)] ----------------
// p(kv) = ((kv&15)>>2)*8 + (kv&3) + 4*(kv>>4) within each 32-block, matching
// the attention kernel's in-register P fragment order (exact relabeling).
__global__ void transpose_v_k(const u16* __restrict__ in, u16* __restrict__ out) {
  __shared__ u16 tile[32][33];
  int s0 = blockIdx.y * 32, c0 = blockIdx.x * 32;
  int b = blockIdx.z;
  int tx = threadIdx.x, ty = threadIdx.y;
  const u16* vin = in + (size_t)b * SEQ * DIM;
  u16* vout = out + (size_t)b * SEQ * DIM;
  #pragma unroll
  for (int j = 0; j < 32; j += 8)
    tile[ty + j][tx] = vin[(size_t)(s0 + ty + j) * DIM + c0 + tx];
  __syncthreads();
  int sp = s0 + ((tx & 15) >> 2) * 8 + (tx & 3) + 4 * (tx >> 4);
  #pragma unroll
  for (int j = 0; j < 32; j += 8)
    vout[(size_t)(c0 + ty + j) * SEQ + sp] = tile[tx][ty + j];
}

// ---------------- rope tables ----------------
__global__ void rope_table_k(float* __restrict__ ct, float* __restrict__ st) {
  int t = blockIdx.x * 256 + threadIdx.x;
  if (t >= SEQ * 32) return;
  int i = t & 31, s = t >> 5;
  float invf = expf(-(float)i * 0.28782313662425575f);
  float a = (float)s * invf;
  ct[t] = cosf(a);
  st[t] = sinf(a);
}

// ---------------- combine split-K partials ----------------
template<int NS, int OUTF32>
__global__ void combine_k(const float* __restrict__ p, void* __restrict__ out, int n4, int slab4) {
  int t = blockIdx.x * 256 + threadIdx.x;
  if (t >= n4) return;
  float4 a = ((const float4*)p)[t];
  #pragma unroll
  for (int s = 1; s < NS; ++s) {
    float4 b = ((const float4*)p)[t + (size_t)s * slab4];
    a.x += b.x; a.y += b.y; a.z += b.z; a.w += b.w;
  }
  if (OUTF32) ((float4*)out)[t] = a;
  else { u16x4 o = { f2bf(a.x), f2bf(a.y), f2bf(a.z), f2bf(a.w) };
         *(u16x4*)((u16*)out + (size_t)t * 4) = o; }
}

// ---------------- GEMM: C[M][N] = A[M][K] @ BT[N][K]^T ----------------
// MODE 0: bf16 out. MODE 2: q/k merged (z=0: q + RoPE + SCALE_C; z=1: k + RoPE).
// MODE 3: split-K; z = K-slab index; f32 out to Cv + z*M*N (K = slab size).
template<int MODE>
__global__ __launch_bounds__(256)
void gemm_bt(const u16* __restrict__ A, int lda, int a_off,
             const u16* __restrict__ BT, int ldb,
             void* __restrict__ Cv, int M, int N, int K,
             const u16* __restrict__ BT2, void* __restrict__ Cv2, int a_off2,
             const float* __restrict__ ct, const float* __restrict__ st) {
  __shared__ __align__(16) u16 As[128 * 32];
  __shared__ __align__(16) u16 Bs[128 * 32];
  const int tid = threadIdx.x;
  const int lane = tid & 63;
  const int wid = tid >> 6;
  const int z = blockIdx.z;
  if (MODE == 2 && z) { BT = BT2; Cv = Cv2; a_off = a_off2; }
  int koff = (MODE == 3) ? z * K : 0;
  // XCD swizzle within the x-y plane (all grids are multiples of 8)
  const int nb = gridDim.x * gridDim.y;
  int f = blockIdx.x + gridDim.x * blockIdx.y;
  f = (f & 7) * (nb >> 3) + (f >> 3);
  const int m0 = (f / gridDim.x) * 128;
  const int n0 = (f % gridDim.x) * 128;
  const int wr = wid >> 1, wc = wid & 1;
  const int l15 = lane & 15, lg = lane >> 4;
  const int rA = lane >> 2;
  const int kq = (lane & 3) * 8;

  f32x4 acc[4][4] = {};
  const int nk = K / 32;
  for (int kt = 0; kt < nk; ++kt) {
    const int k0 = koff + kt * 32;
    #pragma unroll
    for (int c = 0; c < 2; ++c) {
      int ca = wid * 2 + c;
      const u16* ga = A + (size_t)(m0 + ca * 16 + rA) * lda + a_off + k0 + kq;
      async_copy16(ga, &As[ca * 512]);
      const u16* gb = BT + (size_t)(n0 + ca * 16 + rA) * ldb + k0 + kq;
      async_copy16(gb, &Bs[ca * 512]);
    }
    __syncthreads();
    bf16x8 af[4], bfr[4];
    #pragma unroll
    for (int i = 0; i < 4; ++i) {
      af[i]  = *(const bf16x8*)&As[(wr * 64 + i * 16 + l15) * 32 + lg * 8];
      bfr[i] = *(const bf16x8*)&Bs[(wc * 64 + i * 16 + l15) * 32 + lg * 8];
    }
    #pragma unroll
    for (int i = 0; i < 4; ++i)
      #pragma unroll
      for (int j = 0; j < 4; ++j)
        acc[i][j] = mfma16(af[i], bfr[j], acc[i][j]);
    __syncthreads();
  }

  if (MODE == 2) {
    // fused RoPE epilogue; q (z==0) additionally scaled by SCALE_C
    u16* op = (u16*)Cv;
    const float qs = z ? 1.0f : SCALE_C;
    #pragma unroll
    for (int i = 0; i < 4; ++i) {
      int rowb = m0 + wr * 64 + i * 16 + lg * 4;
      #pragma unroll
      for (int j = 0; j < 2; ++j) {
        int ii = j * 16 + l15;                 // 0..31 within head
        int colb = n0 + wc * 64;
        #pragma unroll
        for (int r = 0; r < 4; ++r) {
          int s = (rowb + r) & (SEQ - 1);
          float c = ct[s * 32 + ii], sn = st[s * 32 + ii];
          float x1 = acc[i][j][r], x2 = acc[i][j + 2][r];
          op[(size_t)(rowb + r) * N + colb + ii]      = f2bf((x1 * c - x2 * sn) * qs);
          op[(size_t)(rowb + r) * N + colb + ii + 32] = f2bf((x2 * c + x1 * sn) * qs);
        }
      }
    }
  } else {
    #pragma unroll
    for (int i = 0; i < 4; ++i) {
      #pragma unroll
      for (int j = 0; j < 4; ++j) {
        int row = m0 + wr * 64 + i * 16 + lg * 4;
        int col = n0 + wc * 64 + j * 16 + l15;
        #pragma unroll
        for (int r = 0; r < 4; ++r) {
          float v = acc[i][j][r];
          if (MODE == 3) ((float*)Cv)[(size_t)z * M * N + (size_t)(row + r) * N + col] = v;
          else           ((u16*)Cv)[(size_t)(row + r) * N + col] = f2bf(v);
        }
      }
    }
  }
}

// ---------------- flash attention v10 ----------------
// 1024 blocks (XCD-swizzled), ONE 64-lane wave per block; wave = 64 q-rows;
// KVB=32; private 3-buffer LDS; ZERO barriers (producer == consumer wave,
// gload_lds -> ds_read ordered purely by counted vmcnt). Halves per-CU LDS
// read bytes vs 2-wave/32-row config (tile reads amortized over 2x q-rows).
#define KVB 32
__global__ __launch_bounds__(64)
void attn_kernel(const u16* __restrict__ Q, const u16* __restrict__ Kb,
                 const u16* __restrict__ VT, u16* __restrict__ O) {
  __shared__ __align__(16) u16 Ks[3][KVB * 64];        // 4KB/buf
  __shared__ __align__(16) u16 Vs[3][HEAD_DIM * KVB];  // 8KB/buf

  const int lane = threadIdx.x & 63;
  int fl = blockIdx.x + 32 * (blockIdx.y + 16 * blockIdx.z);
  fl = (fl & 7) * 128 + (fl >> 3);
  const int q0 = (fl & 31) * 64;
  const int h = (fl >> 5) & 15;
  const int b = fl >> 9;
  const int l15 = lane & 15, lg = lane >> 4;

  const u16* kbp = Kb + (size_t)(b * SEQ) * (HEADS * HALF) + h * HALF;
  const u16* vtb = VT + (size_t)b * SEQ * DIM + (size_t)(h * HEAD_DIM) * SEQ;

  // Q fragments (B-operand; col=l15, k=lg*8+j), 4 q-16 blocks
  bf16x8 qf[4][2];
  #pragma unroll
  for (int mq = 0; mq < 4; ++mq)
    #pragma unroll
    for (int ks = 0; ks < 2; ++ks)
      qf[mq][ks] = *(const bf16x8*)&Q[(size_t)(b * SEQ + q0 + mq * 16 + l15) * (HEADS * HALF)
                                      + h * HALF + ks * 32 + lg * 8];

  f32x4 o[4][8] = {};
  float l_part[4] = {0.f, 0.f, 0.f, 0.f};

  // staging geometry (one wave stages the whole tile)
  const int kRow = lane >> 3;                          // K: 8 rows/instr, 128B rows
  const int kColB = ((lane & 7) ^ kRow) * 16;          // K slot ^ (row&7)
  const int vRow = lane >> 2;                          // V: 16 rows/instr, 64B rows
  const int vColB = ((lane & 3) ^ ((lane >> 3) & 3)) * 16;  // V slot ^ ((row>>1)&3)

  auto stage = [&](u16* KsD, u16* VsD, int kv0) {
    #pragma unroll
    for (int c = 0; c < 4; ++c) {            // K chunks 0..3 (8 rows each)
      const u16* src = kbp + (size_t)(kv0 + c * 8 + kRow) * (HEADS * HALF) + (kColB >> 1);
      async_copy16(src, KsD + c * 512);
    }
    #pragma unroll
    for (int c = 0; c < 8; ++c) {            // V chunks 0..7 (16 rows each)
      const u16* src = vtb + (size_t)(c * 16 + vRow) * SEQ + kv0 + (vColB >> 1);
      async_copy16(src, VsD + c * 512);
    }
  };

  auto compute = [&](const u16* KsP, const u16* VsP) {
    const char* KsB = (const char*)KsP;
    const char* VsB = (const char*)VsP;
    const int kswz = (l15 & 7) << 4;
    // K fragment reads
    bf16x8 kf[2][2];
    #pragma unroll
    for (int ks = 0; ks < 2; ++ks)
      #pragma unroll
      for (int nf = 0; nf < 2; ++nf)
        kf[ks][nf] = *(const bf16x8*)(KsB + (nf * 16 + l15) * 128 + ((ks * 64 + lg * 16) ^ kswz));
    // swapped QK^T: S^T[kv][q], 2 kv-rows x 4 q-cols
    f32x4 s[2][4] = {};
    __builtin_amdgcn_s_setprio(1);
    #pragma unroll
    for (int ks = 0; ks < 2; ++ks)
      #pragma unroll
      for (int nf = 0; nf < 2; ++nf)
        #pragma unroll
        for (int mq = 0; mq < 4; ++mq)
          s[nf][mq] = mfma16(kf[ks][nf], qf[mq][ks], s[nf][mq]);
    __builtin_amdgcn_s_setprio(0);
    // V fragment reads issued now (latency overlaps the exp/cvt work below)
    bf16x8 vf[8];
    #pragma unroll
    for (int db = 0; db < 8; ++db) {
      int row = db * 16 + l15;
      vf[db] = *(const bf16x8*)(VsB + row * 64 + ((lg * 16) ^ (((row >> 1) & 3) << 4)));
    }
    // softmax-lite in-register (Q pre-scaled: exp2 direct)
    bf16x8 pa[4];
    #pragma unroll
    for (int mq = 0; mq < 4; ++mq) {
      float p[8];
      #pragma unroll
      for (int nf = 0; nf < 2; ++nf)
        #pragma unroll
        for (int r = 0; r < 4; ++r) {
          float v = EXP2F(s[nf][mq][r]);
          p[nf * 4 + r] = v;
          l_part[mq] += v;
        }
      union { uint32_t u[4]; bf16x8 v8; } pk;
      asm("v_cvt_pk_bf16_f32 %0, %1, %2" : "=v"(pk.u[0]) : "v"(p[0]), "v"(p[1]));
      asm("v_cvt_pk_bf16_f32 %0, %1, %2" : "=v"(pk.u[1]) : "v"(p[2]), "v"(p[3]));
      asm("v_cvt_pk_bf16_f32 %0, %1, %2" : "=v"(pk.u[2]) : "v"(p[4]), "v"(p[5]));
      asm("v_cvt_pk_bf16_f32 %0, %1, %2" : "=v"(pk.u[3]) : "v"(p[6]), "v"(p[7]));
      pa[mq] = pk.v8;
    }
    // PV
    __builtin_amdgcn_s_setprio(1);
    #pragma unroll
    for (int db = 0; db < 8; ++db)
      #pragma unroll
      for (int mq = 0; mq < 4; ++mq)
        o[mq][db] = mfma16(pa[mq], vf[db], o[mq][db]);
    __builtin_amdgcn_s_setprio(0);
  };

#define WAIT12 asm volatile("s_waitcnt vmcnt(12)" ::: "memory")
#define WAIT0  asm volatile("s_waitcnt vmcnt(0)" ::: "memory")

  // prologue: 12 loads per stage; no barriers anywhere (single-wave block)
  stage(Ks[0], Vs[0], 0);
  stage(Ks[1], Vs[1], KVB);
  WAIT12;                                    // buf0 complete
  int t = 0;
  for (int i = 0; i < 20; ++i) {             // t = 0..59
    stage(Ks[2], Vs[2], (t + 2) * KVB); compute(Ks[0], Vs[0]); WAIT12;
    stage(Ks[0], Vs[0], (t + 3) * KVB); compute(Ks[1], Vs[1]); WAIT12;
    stage(Ks[1], Vs[1], (t + 4) * KVB); compute(Ks[2], Vs[2]); WAIT12;
    t += 3;
  }
  // tail: t = 60..63
  stage(Ks[2], Vs[2], 62 * KVB); compute(Ks[0], Vs[0]); WAIT12;
  stage(Ks[0], Vs[0], 63 * KVB); compute(Ks[1], Vs[1]); WAIT12;
  compute(Ks[2], Vs[2]); WAIT0;
  compute(Ks[0], Vs[0]);

#undef WAIT12
#undef WAIT0

  // deferred row-sum: lane holds partial for q=mq*16+l15 over kv=lg-chunk
  #pragma unroll
  for (int mq = 0; mq < 4; ++mq) {
    float l = l_part[mq];
    l += __shfl_xor(l, 16);
    l += __shfl_xor(l, 32);            // full sum for q = mq*16 + l15
    float inv[4];
    #pragma unroll
    for (int r = 0; r < 4; ++r)
      inv[r] = 1.0f / __shfl(l, lg * 4 + r);   // redistribute to o layout (q=lg*4+r)
    #pragma unroll
    for (int db = 0; db < 8; ++db)
      #pragma unroll
      for (int r = 0; r < 4; ++r) {
        int row = q0 + mq * 16 + lg * 4 + r;
        O[(size_t)(b * SEQ + row) * DIM + h * HEAD_DIM + db * 16 + l15] = f2bf(o[mq][db][r] * inv[r]);
      }
  }
}

// ---------------- host ----------------
extern "C" void kernel_launch(void* const* d_in, const int* in_sizes, int n_in,
                              void* d_out, int out_size, void* d_ws, size_t ws_size,
                              hipStream_t stream) {
  const float* x     = (const float*)d_in[0];
  const float* wq_d  = (const float*)d_in[1];
  const float* wkv_d = (const float*)d_in[2];
  const float* wq_u  = (const float*)d_in[3];
  const float* wk_u  = (const float*)d_in[4];
  const float* wv_u  = (const float*)d_in[5];
  const float* wo    = (const float*)d_in[6];

  char* ws = (char*)d_ws;
  size_t off = 0;
  auto alloc = [&](size_t bytes) -> void* {
    void* p = ws + off;
    off += (bytes + 255) & ~(size_t)255;
    return p;
  };
  u16* xb     = (u16*)alloc((size_t)TOK * DIM * 2);
  u16* wdT    = (u16*)alloc((size_t)512 * DIM * 2);
  u16* wquT   = (u16*)alloc((size_t)1024 * LATENT * 2);
  u16* wkuT   = (u16*)alloc((size_t)1024 * LATENT * 2);
  u16* wvuT   = (u16*)alloc((size_t)DIM * LATENT * 2);
  u16* woT    = (u16*)alloc((size_t)DIM * DIM * 2);
  u16* lat    = (u16*)alloc((size_t)TOK * 512 * 2);
  float* latP = (float*)alloc((size_t)4 * TOK * 512 * 4);   // split-K4 partials
  u16* qb     = (u16*)alloc((size_t)TOK * 1024 * 2);
  u16* kb     = (u16*)alloc((size_t)TOK * 1024 * 2);
  u16* vb     = (u16*)alloc((size_t)TOK * DIM * 2);
  u16* vT     = (u16*)alloc((size_t)TOK * DIM * 2);
  u16* ao     = (u16*)alloc((size_t)TOK * DIM * 2);
  float* ct   = (float*)alloc((size_t)SEQ * 32 * 4);
  float* st   = (float*)alloc((size_t)SEQ * 32 * 4);
  (void)in_sizes; (void)n_in; (void)out_size; (void)ws_size;

  dim3 tb(32, 8);
  conv_f32_bf16_k<<<(TOK * DIM / 4 + 255) / 256, 256, 0, stream>>>(x, xb, TOK * DIM / 4);
  // weight transposes (merged via grid.z)
  transpose_w_k<<<dim3(8, 64, 2), tb, 0, stream>>>(wq_d, wkv_d, wdT, wdT, 256, 256, 2048);
  transpose_w_k<<<dim3(32, 8, 2), tb, 0, stream>>>(wq_u, wk_u, wquT, wkuT, 1024, 0, 256);
  transpose_w_k<<<dim3(64, 8, 1), tb, 0, stream>>>(wv_u, wv_u, wvuT, wvuT, 2048, 0, 256);
  transpose_w_k<<<dim3(64, 64, 1), tb, 0, stream>>>(wo, wo, woT, woT, 2048, 0, 2048);
  rope_table_k<<<(SEQ * 32 + 255) / 256, 256, 0, stream>>>(ct, st);

  // lat = x @ [wq_d|wkv_d], split-K4 -> fp32 partials -> bf16 combine
  gemm_bt<3><<<dim3(4, 32, 4), 256, 0, stream>>>(xb, DIM, 0, wdT, DIM, latP, TOK, 512, 512,
                                                 nullptr, nullptr, 0, nullptr, nullptr);
  combine_k<4, 0><<<(TOK * 512 / 4 + 255) / 256, 256, 0, stream>>>(latP, lat, TOK * 512 / 4, TOK * 512 / 4);

  // q,k up-proj merged (z: 0=q + RoPE + SCALE_C, 1=k + RoPE)
  gemm_bt<2><<<dim3(8, 32, 2), 256, 0, stream>>>(lat, 512, 0, wquT, LATENT, qb, TOK, 1024, LATENT,
                                                 wkuT, kb, 256, ct, st);
  // v up-proj
  gemm_bt<0><<<dim3(16, 32, 1), 256, 0, stream>>>(lat, 512, 256, wvuT, LATENT, vb, TOK, 2048, LATENT,
                                                  nullptr, nullptr, 0, nullptr, nullptr);
  transpose_v_k<<<dim3(DIM / 32, SEQ / 32, BATCH), tb, 0, stream>>>(vb, vT);

  attn_kernel<<<dim3(SEQ / 64, HEADS, BATCH), 64, 0, stream>>>(qb, kb, vT, ao);

  // out = attn_out @ wo — single GEMM, fp32 direct to d_out
  gemm_bt<3><<<dim3(16, 32, 1), 256, 0, stream>>>(ao, DIM, 0, woT, DIM, (float*)d_out, TOK, DIM, DIM,
                                                  nullptr, nullptr, 0, nullptr, nullptr);
}

// Round 11
// 195.642 us; speedup vs baseline: 1.0660x; 1.0660x over previous
//
#include <hip/hip_runtime.h>
#include <stdint.h>

typedef unsigned short u16;
typedef __attribute__((ext_vector_type(8))) short bf16x8;
typedef __attribute__((ext_vector_type(4))) float f32x4;
typedef __attribute__((ext_vector_type(4))) unsigned short u16x4;

#define DIM 2048
#define HEADS 16
#define HEAD_DIM 128
#define HALF 64
#define LATENT 256
#define BATCH 2
#define SEQ 2048
#define TOK (BATCH*SEQ)

#if defined(__has_builtin)
#if __has_builtin(__builtin_amdgcn_exp2f)
#define EXP2F(x) __builtin_amdgcn_exp2f(x)
#endif
#endif
#ifndef EXP2F
#define EXP2F(x) exp2f(x)
#endif

#define SCALE_C 0.18033688011112042f   // (1/sqrt(64)) * log2(e), folded into Q

__device__ __forceinline__ u16 f2bf(float f) {
  uint32_t u = __float_as_uint(f);
  u += 0x7fff + ((u >> 16) & 1);   // round-to-nearest-even
  return (u16)(u >> 16);
}

__device__ __forceinline__ f32x4 mfma16(bf16x8 a, bf16x8 b, f32x4 c) {
  return __builtin_amdgcn_mfma_f32_16x16x32_bf16(a, b, c, 0, 0, 0);
}

__device__ __forceinline__ void async_copy16(const void* g, void* l) {
  __builtin_amdgcn_global_load_lds(
      (const __attribute__((address_space(1))) void*)g,
      (__attribute__((address_space(3))) void*)l, 16, 0, 0);
}

// ---------------- fp32 -> bf16 elementwise ----------------
__global__ void conv_f32_bf16_k(const float* __restrict__ in, u16* __restrict__ out, int n4) {
  int t = blockIdx.x * 256 + threadIdx.x;
  if (t >= n4) return;
  float4 v = ((const float4*)in)[t];
  u16x4 o = { f2bf(v.x), f2bf(v.y), f2bf(v.z), f2bf(v.w) };
  *(u16x4*)(out + (size_t)t * 4) = o;
}

// ---------------- transpose fp32[K][N] -> bf16[N][K], z selects src/dst ----------------
__global__ void transpose_w_k(const float* __restrict__ in0, const float* __restrict__ in1,
                              u16* __restrict__ out0, u16* __restrict__ out1,
                              int N, int row_step, int out_ld) {
  __shared__ float tile[32][33];
  const float* in = blockIdx.z ? in1 : in0;
  u16* out = blockIdx.z ? out1 : out0;
  int row_off = blockIdx.z * row_step;
  int k0 = blockIdx.y * 32, n0 = blockIdx.x * 32;
  int tx = threadIdx.x, ty = threadIdx.y;
  #pragma unroll
  for (int j = 0; j < 32; j += 8)
    tile[ty + j][tx] = in[(size_t)(k0 + ty + j) * N + n0 + tx];
  __syncthreads();
  #pragma unroll
  for (int j = 0; j < 32; j += 8)
    out[(size_t)(n0 + ty + j + row_off) * out_ld + k0 + tx] = f2bf(tile[tx][ty + j]);
}

// ---------------- rope tables ----------------
__global__ void rope_table_k(float* __restrict__ ct, float* __restrict__ st) {
  int t = blockIdx.x * 256 + threadIdx.x;
  if (t >= SEQ * 32) return;
  int i = t & 31, s = t >> 5;
  float invf = expf(-(float)i * 0.28782313662425575f);
  float a = (float)s * invf;
  ct[t] = cosf(a);
  st[t] = sinf(a);
}

// ---------------- combine split-K partials ----------------
template<int NS, int OUTF32>
__global__ void combine_k(const float* __restrict__ p, void* __restrict__ out, int n4, int slab4) {
  int t = blockIdx.x * 256 + threadIdx.x;
  if (t >= n4) return;
  float4 a = ((const float4*)p)[t];
  #pragma unroll
  for (int s = 1; s < NS; ++s) {
    float4 b = ((const float4*)p)[t + (size_t)s * slab4];
    a.x += b.x; a.y += b.y; a.z += b.z; a.w += b.w;
  }
  if (OUTF32) ((float4*)out)[t] = a;
  else { u16x4 o = { f2bf(a.x), f2bf(a.y), f2bf(a.z), f2bf(a.w) };
         *(u16x4*)((u16*)out + (size_t)t * 4) = o; }
}

// ---------------- GEMM: C[M][N] = A[M][K] @ BT[N][K]^T ----------------
// MODE 0: bf16 out. MODE 2: q/k merged (z=0: q + RoPE + SCALE_C; z=1: k + RoPE).
// MODE 3: split-K; z = K-slab index; f32 out to Cv + z*M*N (K = slab size).
// MODE 4: bf16 out written TRANSPOSED+PERMUTED as vT[b][c][p(s)] (v up-proj).
template<int MODE>
__global__ __launch_bounds__(256)
void gemm_bt(const u16* __restrict__ A, int lda, int a_off,
             const u16* __restrict__ BT, int ldb,
             void* __restrict__ Cv, int M, int N, int K,
             const u16* __restrict__ BT2, void* __restrict__ Cv2, int a_off2,
             const float* __restrict__ ct, const float* __restrict__ st) {
  __shared__ __align__(16) u16 As[128 * 32];
  __shared__ __align__(16) u16 Bs[128 * 32];
  const int tid = threadIdx.x;
  const int lane = tid & 63;
  const int wid = tid >> 6;
  const int z = blockIdx.z;
  if (MODE == 2 && z) { BT = BT2; Cv = Cv2; a_off = a_off2; }
  int koff = (MODE == 3) ? z * K : 0;
  // XCD swizzle within the x-y plane (all grids are multiples of 8)
  const int nb = gridDim.x * gridDim.y;
  int f = blockIdx.x + gridDim.x * blockIdx.y;
  f = (f & 7) * (nb >> 3) + (f >> 3);
  const int m0 = (f / gridDim.x) * 128;
  const int n0 = (f % gridDim.x) * 128;
  const int wr = wid >> 1, wc = wid & 1;
  const int l15 = lane & 15, lg = lane >> 4;
  const int rA = lane >> 2;
  const int kq = (lane & 3) * 8;

  f32x4 acc[4][4] = {};
  const int nk = K / 32;
  for (int kt = 0; kt < nk; ++kt) {
    const int k0 = koff + kt * 32;
    #pragma unroll
    for (int c = 0; c < 2; ++c) {
      int ca = wid * 2 + c;
      const u16* ga = A + (size_t)(m0 + ca * 16 + rA) * lda + a_off + k0 + kq;
      async_copy16(ga, &As[ca * 512]);
      const u16* gb = BT + (size_t)(n0 + ca * 16 + rA) * ldb + k0 + kq;
      async_copy16(gb, &Bs[ca * 512]);
    }
    __syncthreads();
    bf16x8 af[4], bfr[4];
    #pragma unroll
    for (int i = 0; i < 4; ++i) {
      af[i]  = *(const bf16x8*)&As[(wr * 64 + i * 16 + l15) * 32 + lg * 8];
      bfr[i] = *(const bf16x8*)&Bs[(wc * 64 + i * 16 + l15) * 32 + lg * 8];
    }
    #pragma unroll
    for (int i = 0; i < 4; ++i)
      #pragma unroll
      for (int j = 0; j < 4; ++j)
        acc[i][j] = mfma16(af[i], bfr[j], acc[i][j]);
    __syncthreads();
  }

  if (MODE == 2) {
    // fused RoPE epilogue; q (z==0) additionally scaled by SCALE_C
    u16* op = (u16*)Cv;
    const float qs = z ? 1.0f : SCALE_C;
    #pragma unroll
    for (int i = 0; i < 4; ++i) {
      int rowb = m0 + wr * 64 + i * 16 + lg * 4;
      #pragma unroll
      for (int j = 0; j < 2; ++j) {
        int ii = j * 16 + l15;                 // 0..31 within head
        int colb = n0 + wc * 64;
        #pragma unroll
        for (int r = 0; r < 4; ++r) {
          int s = (rowb + r) & (SEQ - 1);
          float c = ct[s * 32 + ii], sn = st[s * 32 + ii];
          float x1 = acc[i][j][r], x2 = acc[i][j + 2][r];
          op[(size_t)(rowb + r) * N + colb + ii]      = f2bf((x1 * c - x2 * sn) * qs);
          op[(size_t)(rowb + r) * N + colb + ii + 32] = f2bf((x2 * c + x1 * sn) * qs);
        }
      }
    }
  } else if (MODE == 4) {
    // transposed+permuted write: vT[b][c][p(s)], p(s) consecutive over r
    u16* op = (u16*)Cv;
    const int bb = m0 >> 11;                   // batch (tile never straddles)
    #pragma unroll
    for (int i = 0; i < 4; ++i) {
      int rowb = m0 + wr * 64 + i * 16 + lg * 4;   // token, ≡0 mod 4
      int s = rowb & (SEQ - 1);
      int pbase = (s & ~31) + (((s & 15) >> 2) << 3) + (((s >> 4) & 1) << 2);
      #pragma unroll
      for (int j = 0; j < 4; ++j) {
        int c = n0 + wc * 64 + j * 16 + l15;
        u16x4 ov = { f2bf(acc[i][j][0]), f2bf(acc[i][j][1]),
                     f2bf(acc[i][j][2]), f2bf(acc[i][j][3]) };
        *(u16x4*)&op[(size_t)bb * SEQ * DIM + (size_t)c * SEQ + pbase] = ov;
      }
    }
  } else {
    #pragma unroll
    for (int i = 0; i < 4; ++i) {
      #pragma unroll
      for (int j = 0; j < 4; ++j) {
        int row = m0 + wr * 64 + i * 16 + lg * 4;
        int col = n0 + wc * 64 + j * 16 + l15;
        #pragma unroll
        for (int r = 0; r < 4; ++r) {
          float v = acc[i][j][r];
          if (MODE == 3) ((float*)Cv)[(size_t)z * M * N + (size_t)(row + r) * N + col] = v;
          else           ((u16*)Cv)[(size_t)(row + r) * N + col] = f2bf(v);
        }
      }
    }
  }
}

// ---------------- flash attention v9 (best measured config, reverted) ----------------
// 1024 blocks (XCD-swizzled), 128 thr / 2 waves; wave = 32 q-rows; KVB=32.
// Swapped QK^T (register P, V position-permuted), 3-buf counted-vmcnt pipeline,
// static buffer pointers, batched ds_reads. Q pre-scaled by SCALE_C.
#define KVB 32
__global__ __launch_bounds__(128, 2)
void attn_kernel(const u16* __restrict__ Q, const u16* __restrict__ Kb,
                 const u16* __restrict__ VT, u16* __restrict__ O) {
  __shared__ __align__(16) u16 Ks[3][KVB * 64];        // 4KB/buf
  __shared__ __align__(16) u16 Vs[3][HEAD_DIM * KVB];  // 8KB/buf

  const int tid = threadIdx.x, lane = tid & 63, wid = tid >> 6;
  int fl = blockIdx.x + 32 * (blockIdx.y + 16 * blockIdx.z);
  fl = (fl & 7) * 128 + (fl >> 3);
  const int q0 = (fl & 31) * 64;
  const int h = (fl >> 5) & 15;
  const int b = fl >> 9;
  const int l15 = lane & 15, lg = lane >> 4;

  const u16* kbp = Kb + (size_t)(b * SEQ) * (HEADS * HALF) + h * HALF;
  const u16* vtb = VT + (size_t)b * SEQ * DIM + (size_t)(h * HEAD_DIM) * SEQ;

  // Q fragments (B-operand; col=l15, k=lg*8+j)
  bf16x8 qf[2][2];
  #pragma unroll
  for (int m = 0; m < 2; ++m)
    #pragma unroll
    for (int ks = 0; ks < 2; ++ks)
      qf[m][ks] = *(const bf16x8*)&Q[(size_t)(b * SEQ + q0 + wid * 32 + m * 16 + l15) * (HEADS * HALF)
                                     + h * HALF + ks * 32 + lg * 8];

  f32x4 o[2][8] = {};
  float l_part[2] = {0.f, 0.f};

  // staging geometry
  const int kRow = lane >> 3;                          // K: 8 rows/instr, 128B rows
  const int kColB = ((lane & 7) ^ kRow) * 16;          // K slot ^ (row&7)
  const int vRow = lane >> 2;                          // V: 16 rows/instr, 64B rows
  const int vColB = ((lane & 3) ^ ((lane >> 3) & 3)) * 16;  // V slot ^ ((row>>1)&3)

  auto stage = [&](u16* KsD, u16* VsD, int kv0) {
    #pragma unroll
    for (int i = 0; i < 2; ++i) {            // K chunks: wave w -> {2w, 2w+1}
      int c = wid * 2 + i;
      const u16* src = kbp + (size_t)(kv0 + c * 8 + kRow) * (HEADS * HALF) + (kColB >> 1);
      async_copy16(src, KsD + c * 512);
    }
    #pragma unroll
    for (int i = 0; i < 4; ++i) {            // V chunks: wave w -> {4w..4w+3}
      int c = wid * 4 + i;
      const u16* src = vtb + (size_t)(c * 16 + vRow) * SEQ + kv0 + (vColB >> 1);
      async_copy16(src, VsD + c * 512);
    }
  };

  auto compute = [&](const u16* KsP, const u16* VsP) {
    const char* KsB = (const char*)KsP;
    const char* VsB = (const char*)VsP;
    const int kswz = (l15 & 7) << 4;
    // batch-issue ALL LDS reads first (max distance to first use)
    bf16x8 kf[2][2], vf[8];
    #pragma unroll
    for (int ks = 0; ks < 2; ++ks)
      #pragma unroll
      for (int nf = 0; nf < 2; ++nf)
        kf[ks][nf] = *(const bf16x8*)(KsB + (nf * 16 + l15) * 128 + ((ks * 64 + lg * 16) ^ kswz));
    #pragma unroll
    for (int db = 0; db < 8; ++db) {
      int row = db * 16 + l15;
      vf[db] = *(const bf16x8*)(VsB + row * 64 + ((lg * 16) ^ (((row >> 1) & 3) << 4)));
    }
    // swapped QK^T: S^T[kv][q]
    f32x4 s[2][2] = {};
    __builtin_amdgcn_s_setprio(1);
    #pragma unroll
    for (int ks = 0; ks < 2; ++ks)
      #pragma unroll
      for (int nf = 0; nf < 2; ++nf) {
        s[0][nf] = mfma16(kf[ks][nf], qf[0][ks], s[0][nf]);
        s[1][nf] = mfma16(kf[ks][nf], qf[1][ks], s[1][nf]);
      }
    __builtin_amdgcn_s_setprio(0);
    // softmax-lite in-register (Q pre-scaled: exp2 direct)
    bf16x8 pa[2];
    #pragma unroll
    for (int m = 0; m < 2; ++m) {
      float p[8];
      #pragma unroll
      for (int nf = 0; nf < 2; ++nf)
        #pragma unroll
        for (int r = 0; r < 4; ++r) {
          float v = EXP2F(s[m][nf][r]);
          p[nf * 4 + r] = v;
          l_part[m] += v;
        }
      union { uint32_t u[4]; bf16x8 v8; } pk;
      asm("v_cvt_pk_bf16_f32 %0, %1, %2" : "=v"(pk.u[0]) : "v"(p[0]), "v"(p[1]));
      asm("v_cvt_pk_bf16_f32 %0, %1, %2" : "=v"(pk.u[1]) : "v"(p[2]), "v"(p[3]));
      asm("v_cvt_pk_bf16_f32 %0, %1, %2" : "=v"(pk.u[2]) : "v"(p[4]), "v"(p[5]));
      asm("v_cvt_pk_bf16_f32 %0, %1, %2" : "=v"(pk.u[3]) : "v"(p[6]), "v"(p[7]));
      pa[m] = pk.v8;
    }
    // PV
    __builtin_amdgcn_s_setprio(1);
    #pragma unroll
    for (int db = 0; db < 8; ++db) {
      o[0][db] = mfma16(pa[0], vf[db], o[0][db]);
      o[1][db] = mfma16(pa[1], vf[db], o[1][db]);
    }
    __builtin_amdgcn_s_setprio(0);
  };

#define WAIT6 asm volatile("s_waitcnt vmcnt(6)" ::: "memory")
#define WAIT0 asm volatile("s_waitcnt vmcnt(0)" ::: "memory")
#define BAR   __builtin_amdgcn_s_barrier()

  // prologue
  stage(Ks[0], Vs[0], 0);
  stage(Ks[1], Vs[1], KVB);
  WAIT6; BAR;
  // main: t = 0..59 in triples (all stages valid, all waits counted)
  int t = 0;
  for (int i = 0; i < 20; ++i) {
    stage(Ks[2], Vs[2], (t + 2) * KVB); compute(Ks[0], Vs[0]); WAIT6; BAR;
    stage(Ks[0], Vs[0], (t + 3) * KVB); compute(Ks[1], Vs[1]); WAIT6; BAR;
    stage(Ks[1], Vs[1], (t + 4) * KVB); compute(Ks[2], Vs[2]); WAIT6; BAR;
    t += 3;
  }
  // tail: t = 60..63
  stage(Ks[2], Vs[2], 62 * KVB); compute(Ks[0], Vs[0]); WAIT6; BAR;
  stage(Ks[0], Vs[0], 63 * KVB); compute(Ks[1], Vs[1]); WAIT6; BAR;
  compute(Ks[2], Vs[2]); WAIT0; BAR;
  compute(Ks[0], Vs[0]);

#undef WAIT6
#undef WAIT0
#undef BAR

  // deferred row-sum: lane holds partial for q=m*16+l15 over kv=lg-chunk
  #pragma unroll
  for (int m = 0; m < 2; ++m) {
    float l = l_part[m];
    l += __shfl_xor(l, 16);
    l += __shfl_xor(l, 32);            // full sum for q = m*16 + l15
    float inv[4];
    #pragma unroll
    for (int r = 0; r < 4; ++r)
      inv[r] = 1.0f / __shfl(l, lg * 4 + r);   // redistribute to o layout (q=lg*4+r)
    #pragma unroll
    for (int db = 0; db < 8; ++db)
      #pragma unroll
      for (int r = 0; r < 4; ++r) {
        int row = q0 + wid * 32 + m * 16 + lg * 4 + r;
        O[(size_t)(b * SEQ + row) * DIM + h * HEAD_DIM + db * 16 + l15] = f2bf(o[m][db][r] * inv[r]);
      }
  }
}

// ---------------- host ----------------
extern "C" void kernel_launch(void* const* d_in, const int* in_sizes, int n_in,
                              void* d_out, int out_size, void* d_ws, size_t ws_size,
                              hipStream_t stream) {
  const float* x     = (const float*)d_in[0];
  const float* wq_d  = (const float*)d_in[1];
  const float* wkv_d = (const float*)d_in[2];
  const float* wq_u  = (const float*)d_in[3];
  const float* wk_u  = (const float*)d_in[4];
  const float* wv_u  = (const float*)d_in[5];
  const float* wo    = (const float*)d_in[6];

  char* ws = (char*)d_ws;
  size_t off = 0;
  auto alloc = [&](size_t bytes) -> void* {
    void* p = ws + off;
    off += (bytes + 255) & ~(size_t)255;
    return p;
  };
  u16* xb     = (u16*)alloc((size_t)TOK * DIM * 2);
  u16* wdT    = (u16*)alloc((size_t)512 * DIM * 2);
  u16* wquT   = (u16*)alloc((size_t)1024 * LATENT * 2);
  u16* wkuT   = (u16*)alloc((size_t)1024 * LATENT * 2);
  u16* wvuT   = (u16*)alloc((size_t)DIM * LATENT * 2);
  u16* woT    = (u16*)alloc((size_t)DIM * DIM * 2);
  u16* lat    = (u16*)alloc((size_t)TOK * 512 * 2);
  float* latP = (float*)alloc((size_t)4 * TOK * 512 * 4);   // split-K4 partials
  u16* qb     = (u16*)alloc((size_t)TOK * 1024 * 2);
  u16* kb     = (u16*)alloc((size_t)TOK * 1024 * 2);
  u16* vT     = (u16*)alloc((size_t)TOK * DIM * 2);
  u16* ao     = (u16*)alloc((size_t)TOK * DIM * 2);
  float* ct   = (float*)alloc((size_t)SEQ * 32 * 4);
  float* st   = (float*)alloc((size_t)SEQ * 32 * 4);
  (void)in_sizes; (void)n_in; (void)out_size; (void)ws_size;

  dim3 tb(32, 8);
  conv_f32_bf16_k<<<(TOK * DIM / 4 + 255) / 256, 256, 0, stream>>>(x, xb, TOK * DIM / 4);
  // weight transposes (merged via grid.z)
  transpose_w_k<<<dim3(8, 64, 2), tb, 0, stream>>>(wq_d, wkv_d, wdT, wdT, 256, 256, 2048);
  transpose_w_k<<<dim3(32, 8, 2), tb, 0, stream>>>(wq_u, wk_u, wquT, wkuT, 1024, 0, 256);
  transpose_w_k<<<dim3(64, 8, 1), tb, 0, stream>>>(wv_u, wv_u, wvuT, wvuT, 2048, 0, 256);
  transpose_w_k<<<dim3(64, 64, 1), tb, 0, stream>>>(wo, wo, woT, woT, 2048, 0, 2048);
  rope_table_k<<<(SEQ * 32 + 255) / 256, 256, 0, stream>>>(ct, st);

  // lat = x @ [wq_d|wkv_d], split-K4 -> fp32 partials -> bf16 combine
  gemm_bt<3><<<dim3(4, 32, 4), 256, 0, stream>>>(xb, DIM, 0, wdT, DIM, latP, TOK, 512, 512,
                                                 nullptr, nullptr, 0, nullptr, nullptr);
  combine_k<4, 0><<<(TOK * 512 / 4 + 255) / 256, 256, 0, stream>>>(latP, lat, TOK * 512 / 4, TOK * 512 / 4);

  // q,k up-proj merged (z: 0=q + RoPE + SCALE_C, 1=k + RoPE)
  gemm_bt<2><<<dim3(8, 32, 2), 256, 0, stream>>>(lat, 512, 0, wquT, LATENT, qb, TOK, 1024, LATENT,
                                                 wkuT, kb, 256, ct, st);
  // v up-proj with fused transposed+permuted vT write (MODE 4)
  gemm_bt<4><<<dim3(16, 32, 1), 256, 0, stream>>>(lat, 512, 256, wvuT, LATENT, vT, TOK, 2048, LATENT,
                                                  nullptr, nullptr, 0, nullptr, nullptr);

  attn_kernel<<<dim3(SEQ / 64, HEADS, BATCH), 128, 0, stream>>>(qb, kb, vT, ao);

  // out = attn_out @ wo — single GEMM, fp32 direct to d_out
  gemm_bt<3><<<dim3(16, 32, 1), 256, 0, stream>>>(ao, DIM, 0, woT, DIM, (float*)d_out, TOK, DIM, DIM,
                                                  nullptr, nullptr, 0, nullptr, nullptr);
}

// Round 12
// 185.783 us; speedup vs baseline: 1.1226x; 1.0531x over previous
//
#include <hip/hip_runtime.h>
#include <stdint.h>

typedef unsigned short u16;
typedef __attribute__((ext_vector_type(8))) short bf16x8;
typedef __attribute__((ext_vector_type(4))) float f32x4;
typedef __attribute__((ext_vector_type(4))) unsigned short u16x4;

#define DIM 2048
#define HEADS 16
#define HEAD_DIM 128
#define HALF 64
#define LATENT 256
#define BATCH 2
#define SEQ 2048
#define TOK (BATCH*SEQ)

#if defined(__has_builtin)
#if __has_builtin(__builtin_amdgcn_exp2f)
#define EXP2F(x) __builtin_amdgcn_exp2f(x)
#endif
#endif
#ifndef EXP2F
#define EXP2F(x) exp2f(x)
#endif

#define SCALE_C 0.18033688011112042f   // (1/sqrt(64)) * log2(e), folded into Q

__device__ __forceinline__ u16 f2bf(float f) {
  uint32_t u = __float_as_uint(f);
  u += 0x7fff + ((u >> 16) & 1);   // round-to-nearest-even
  return (u16)(u >> 16);
}

__device__ __forceinline__ f32x4 mfma16(bf16x8 a, bf16x8 b, f32x4 c) {
  return __builtin_amdgcn_mfma_f32_16x16x32_bf16(a, b, c, 0, 0, 0);
}

__device__ __forceinline__ void async_copy16(const void* g, void* l) {
  __builtin_amdgcn_global_load_lds(
      (const __attribute__((address_space(1))) void*)g,
      (__attribute__((address_space(3))) void*)l, 16, 0, 0);
}

// ---------------- fused prep: 4 weight transposes + rope tables ----------------
// flat grid, 256 threads (32x8). Segments:
//   [0,1024)    wq_d/wkv_d (2048x256) -> wdT rows z*256, ld 2048   (8x64 x z2)
//   [1024,1536) wq_u/wk_u  (256x1024) -> wquT/wkuT, ld 256         (32x8 x z2)
//   [1536,2048) wv_u       (256x2048) -> wvuT, ld 256              (64x8)
//   [2048,6144) wo         (2048x2048)-> woT, ld 2048              (64x64)
//   [6144,6400) rope tables (65536 entries / 256)
__global__ void prep_k(const float* __restrict__ wq_d, const float* __restrict__ wkv_d,
                       const float* __restrict__ wq_u, const float* __restrict__ wk_u,
                       const float* __restrict__ wv_u, const float* __restrict__ wo,
                       u16* __restrict__ wdT, u16* __restrict__ wquT, u16* __restrict__ wkuT,
                       u16* __restrict__ wvuT, u16* __restrict__ woT,
                       float* __restrict__ ct, float* __restrict__ st) {
  __shared__ float tile[32][33];
  const int f = blockIdx.x;
  const int tx = threadIdx.x, ty = threadIdx.y;

  const float* in = nullptr;
  u16* out = nullptr;
  int N = 0, row_off = 0, out_ld = 0, bx = 0, by = 0;

  if (f < 1024) {
    int z = f >> 9, r = f & 511;
    bx = r & 7; by = r >> 3;
    in = z ? wkv_d : wq_d; out = wdT; row_off = z * 256; N = 256; out_ld = 2048;
  } else if (f < 1536) {
    int r = f - 1024; int z = r >> 8; r &= 255;
    bx = r & 31; by = r >> 5;
    in = z ? wk_u : wq_u; out = z ? wkuT : wquT; row_off = 0; N = 1024; out_ld = 256;
  } else if (f < 2048) {
    int r = f - 1536;
    bx = r & 63; by = r >> 6;
    in = wv_u; out = wvuT; row_off = 0; N = 2048; out_ld = 256;
  } else if (f < 6144) {
    int r = f - 2048;
    bx = r & 63; by = r >> 6;
    in = wo; out = woT; row_off = 0; N = 2048; out_ld = 2048;
  } else {
    int t = (f - 6144) * 256 + ty * 32 + tx;
    int i = t & 31, s = t >> 5;
    float invf = expf(-(float)i * 0.28782313662425575f);
    float a = (float)s * invf;
    ct[t] = cosf(a);
    st[t] = sinf(a);
    return;
  }
  int k0 = by * 32, n0 = bx * 32;
  #pragma unroll
  for (int j = 0; j < 32; j += 8)
    tile[ty + j][tx] = in[(size_t)(k0 + ty + j) * N + n0 + tx];
  __syncthreads();
  #pragma unroll
  for (int j = 0; j < 32; j += 8)
    out[(size_t)(n0 + ty + j + row_off) * out_ld + k0 + tx] = f2bf(tile[tx][ty + j]);
}

// ---------------- combine split-K partials ----------------
template<int NS, int OUTF32>
__global__ void combine_k(const float* __restrict__ p, void* __restrict__ out, int n4, int slab4) {
  int t = blockIdx.x * 256 + threadIdx.x;
  if (t >= n4) return;
  float4 a = ((const float4*)p)[t];
  #pragma unroll
  for (int s = 1; s < NS; ++s) {
    float4 b = ((const float4*)p)[t + (size_t)s * slab4];
    a.x += b.x; a.y += b.y; a.z += b.z; a.w += b.w;
  }
  if (OUTF32) ((float4*)out)[t] = a;
  else { u16x4 o = { f2bf(a.x), f2bf(a.y), f2bf(a.z), f2bf(a.w) };
         *(u16x4*)((u16*)out + (size_t)t * 4) = o; }
}

// ---------------- GEMM: C[M][N] = A[M][K] @ BT[N][K]^T ----------------
// MODE 0: bf16 out. MODE 2: q/k merged (z=0: q + RoPE + SCALE_C; z=1: k + RoPE).
// MODE 3: split-K; z = K-slab index; f32 out to Cv + z*M*N (K = slab size).
// MODE 4: bf16 out written TRANSPOSED+PERMUTED as vT[b][c][p(s)] (v up-proj).
// MODE 5: like MODE 3 but A is fp32 (reg-staged with in-flight bf16 convert).
template<int MODE>
__global__ __launch_bounds__(256)
void gemm_bt(const u16* __restrict__ A, int lda, int a_off,
             const u16* __restrict__ BT, int ldb,
             void* __restrict__ Cv, int M, int N, int K,
             const u16* __restrict__ BT2, void* __restrict__ Cv2, int a_off2,
             const float* __restrict__ ct, const float* __restrict__ st) {
  __shared__ __align__(16) u16 As[128 * 32];
  __shared__ __align__(16) u16 Bs[128 * 32];
  const int tid = threadIdx.x;
  const int lane = tid & 63;
  const int wid = tid >> 6;
  const int z = blockIdx.z;
  if (MODE == 2 && z) { BT = BT2; Cv = Cv2; a_off = a_off2; }
  int koff = (MODE == 3 || MODE == 5) ? z * K : 0;
  // XCD swizzle within the x-y plane (all grids are multiples of 8)
  const int nb = gridDim.x * gridDim.y;
  int f = blockIdx.x + gridDim.x * blockIdx.y;
  f = (f & 7) * (nb >> 3) + (f >> 3);
  const int m0 = (f / gridDim.x) * 128;
  const int n0 = (f % gridDim.x) * 128;
  const int wr = wid >> 1, wc = wid & 1;
  const int l15 = lane & 15, lg = lane >> 4;
  const int rA = lane >> 2;
  const int kq = (lane & 3) * 8;

  f32x4 acc[4][4] = {};
  const int nk = K / 32;
  for (int kt = 0; kt < nk; ++kt) {
    const int k0 = koff + kt * 32;
    #pragma unroll
    for (int c = 0; c < 2; ++c) {
      int ca = wid * 2 + c;
      if (MODE == 5) {
        const float* Af = (const float*)A;
        const float* ga = Af + (size_t)(m0 + ca * 16 + rA) * lda + a_off + k0 + kq;
        float4 v0 = *(const float4*)ga;
        float4 v1 = *(const float4*)(ga + 4);
        union { u16 h[8]; bf16x8 v; } pk;
        pk.h[0] = f2bf(v0.x); pk.h[1] = f2bf(v0.y); pk.h[2] = f2bf(v0.z); pk.h[3] = f2bf(v0.w);
        pk.h[4] = f2bf(v1.x); pk.h[5] = f2bf(v1.y); pk.h[6] = f2bf(v1.z); pk.h[7] = f2bf(v1.w);
        *(bf16x8*)&As[ca * 512 + rA * 32 + kq] = pk.v;
      } else {
        const u16* ga = A + (size_t)(m0 + ca * 16 + rA) * lda + a_off + k0 + kq;
        async_copy16(ga, &As[ca * 512]);
      }
      const u16* gb = BT + (size_t)(n0 + ca * 16 + rA) * ldb + k0 + kq;
      async_copy16(gb, &Bs[ca * 512]);
    }
    __syncthreads();
    bf16x8 af[4], bfr[4];
    #pragma unroll
    for (int i = 0; i < 4; ++i) {
      af[i]  = *(const bf16x8*)&As[(wr * 64 + i * 16 + l15) * 32 + lg * 8];
      bfr[i] = *(const bf16x8*)&Bs[(wc * 64 + i * 16 + l15) * 32 + lg * 8];
    }
    #pragma unroll
    for (int i = 0; i < 4; ++i)
      #pragma unroll
      for (int j = 0; j < 4; ++j)
        acc[i][j] = mfma16(af[i], bfr[j], acc[i][j]);
    __syncthreads();
  }

  if (MODE == 2) {
    // fused RoPE epilogue; q (z==0) additionally scaled by SCALE_C
    u16* op = (u16*)Cv;
    const float qs = z ? 1.0f : SCALE_C;
    #pragma unroll
    for (int i = 0; i < 4; ++i) {
      int rowb = m0 + wr * 64 + i * 16 + lg * 4;
      #pragma unroll
      for (int j = 0; j < 2; ++j) {
        int ii = j * 16 + l15;                 // 0..31 within head
        int colb = n0 + wc * 64;
        #pragma unroll
        for (int r = 0; r < 4; ++r) {
          int s = (rowb + r) & (SEQ - 1);
          float c = ct[s * 32 + ii], sn = st[s * 32 + ii];
          float x1 = acc[i][j][r], x2 = acc[i][j + 2][r];
          op[(size_t)(rowb + r) * N + colb + ii]      = f2bf((x1 * c - x2 * sn) * qs);
          op[(size_t)(rowb + r) * N + colb + ii + 32] = f2bf((x2 * c + x1 * sn) * qs);
        }
      }
    }
  } else if (MODE == 4) {
    // transposed+permuted write: vT[b][c][p(s)], p(s) consecutive over r
    u16* op = (u16*)Cv;
    const int bb = m0 >> 11;                   // batch (tile never straddles)
    #pragma unroll
    for (int i = 0; i < 4; ++i) {
      int rowb = m0 + wr * 64 + i * 16 + lg * 4;   // token, ≡0 mod 4
      int s = rowb & (SEQ - 1);
      int pbase = (s & ~31) + (((s & 15) >> 2) << 3) + (((s >> 4) & 1) << 2);
      #pragma unroll
      for (int j = 0; j < 4; ++j) {
        int c = n0 + wc * 64 + j * 16 + l15;
        u16x4 ov = { f2bf(acc[i][j][0]), f2bf(acc[i][j][1]),
                     f2bf(acc[i][j][2]), f2bf(acc[i][j][3]) };
        *(u16x4*)&op[(size_t)bb * SEQ * DIM + (size_t)c * SEQ + pbase] = ov;
      }
    }
  } else {
    #pragma unroll
    for (int i = 0; i < 4; ++i) {
      #pragma unroll
      for (int j = 0; j < 4; ++j) {
        int row = m0 + wr * 64 + i * 16 + lg * 4;
        int col = n0 + wc * 64 + j * 16 + l15;
        #pragma unroll
        for (int r = 0; r < 4; ++r) {
          float v = acc[i][j][r];
          if (MODE == 3 || MODE == 5) ((float*)Cv)[(size_t)z * M * N + (size_t)(row + r) * N + col] = v;
          else                        ((u16*)Cv)[(size_t)(row + r) * N + col] = f2bf(v);
        }
      }
    }
  }
}

// ---------------- flash attention v9 (best measured config) ----------------
// 1024 blocks (XCD-swizzled), 128 thr / 2 waves; wave = 32 q-rows; KVB=32.
// Swapped QK^T (register P, V position-permuted), 3-buf counted-vmcnt pipeline,
// static buffer pointers, batched ds_reads. Q pre-scaled by SCALE_C.
#define KVB 32
__global__ __launch_bounds__(128, 2)
void attn_kernel(const u16* __restrict__ Q, const u16* __restrict__ Kb,
                 const u16* __restrict__ VT, u16* __restrict__ O) {
  __shared__ __align__(16) u16 Ks[3][KVB * 64];        // 4KB/buf
  __shared__ __align__(16) u16 Vs[3][HEAD_DIM * KVB];  // 8KB/buf

  const int tid = threadIdx.x, lane = tid & 63, wid = tid >> 6;
  int fl = blockIdx.x + 32 * (blockIdx.y + 16 * blockIdx.z);
  fl = (fl & 7) * 128 + (fl >> 3);
  const int q0 = (fl & 31) * 64;
  const int h = (fl >> 5) & 15;
  const int b = fl >> 9;
  const int l15 = lane & 15, lg = lane >> 4;

  const u16* kbp = Kb + (size_t)(b * SEQ) * (HEADS * HALF) + h * HALF;
  const u16* vtb = VT + (size_t)b * SEQ * DIM + (size_t)(h * HEAD_DIM) * SEQ;

  // Q fragments (B-operand; col=l15, k=lg*8+j)
  bf16x8 qf[2][2];
  #pragma unroll
  for (int m = 0; m < 2; ++m)
    #pragma unroll
    for (int ks = 0; ks < 2; ++ks)
      qf[m][ks] = *(const bf16x8*)&Q[(size_t)(b * SEQ + q0 + wid * 32 + m * 16 + l15) * (HEADS * HALF)
                                     + h * HALF + ks * 32 + lg * 8];

  f32x4 o[2][8] = {};
  float l_part[2] = {0.f, 0.f};

  // staging geometry
  const int kRow = lane >> 3;                          // K: 8 rows/instr, 128B rows
  const int kColB = ((lane & 7) ^ kRow) * 16;          // K slot ^ (row&7)
  const int vRow = lane >> 2;                          // V: 16 rows/instr, 64B rows
  const int vColB = ((lane & 3) ^ ((lane >> 3) & 3)) * 16;  // V slot ^ ((row>>1)&3)

  auto stage = [&](u16* KsD, u16* VsD, int kv0) {
    #pragma unroll
    for (int i = 0; i < 2; ++i) {            // K chunks: wave w -> {2w, 2w+1}
      int c = wid * 2 + i;
      const u16* src = kbp + (size_t)(kv0 + c * 8 + kRow) * (HEADS * HALF) + (kColB >> 1);
      async_copy16(src, KsD + c * 512);
    }
    #pragma unroll
    for (int i = 0; i < 4; ++i) {            // V chunks: wave w -> {4w..4w+3}
      int c = wid * 4 + i;
      const u16* src = vtb + (size_t)(c * 16 + vRow) * SEQ + kv0 + (vColB >> 1);
      async_copy16(src, VsD + c * 512);
    }
  };

  auto compute = [&](const u16* KsP, const u16* VsP) {
    const char* KsB = (const char*)KsP;
    const char* VsB = (const char*)VsP;
    const int kswz = (l15 & 7) << 4;
    // batch-issue ALL LDS reads first (max distance to first use)
    bf16x8 kf[2][2], vf[8];
    #pragma unroll
    for (int ks = 0; ks < 2; ++ks)
      #pragma unroll
      for (int nf = 0; nf < 2; ++nf)
        kf[ks][nf] = *(const bf16x8*)(KsB + (nf * 16 + l15) * 128 + ((ks * 64 + lg * 16) ^ kswz));
    #pragma unroll
    for (int db = 0; db < 8; ++db) {
      int row = db * 16 + l15;
      vf[db] = *(const bf16x8*)(VsB + row * 64 + ((lg * 16) ^ (((row >> 1) & 3) << 4)));
    }
    // swapped QK^T: S^T[kv][q]
    f32x4 s[2][2] = {};
    __builtin_amdgcn_s_setprio(1);
    #pragma unroll
    for (int ks = 0; ks < 2; ++ks)
      #pragma unroll
      for (int nf = 0; nf < 2; ++nf) {
        s[0][nf] = mfma16(kf[ks][nf], qf[0][ks], s[0][nf]);
        s[1][nf] = mfma16(kf[ks][nf], qf[1][ks], s[1][nf]);
      }
    __builtin_amdgcn_s_setprio(0);
    // softmax-lite in-register (Q pre-scaled: exp2 direct)
    bf16x8 pa[2];
    #pragma unroll
    for (int m = 0; m < 2; ++m) {
      float p[8];
      #pragma unroll
      for (int nf = 0; nf < 2; ++nf)
        #pragma unroll
        for (int r = 0; r < 4; ++r) {
          float v = EXP2F(s[m][nf][r]);
          p[nf * 4 + r] = v;
          l_part[m] += v;
        }
      union { uint32_t u[4]; bf16x8 v8; } pk;
      asm("v_cvt_pk_bf16_f32 %0, %1, %2" : "=v"(pk.u[0]) : "v"(p[0]), "v"(p[1]));
      asm("v_cvt_pk_bf16_f32 %0, %1, %2" : "=v"(pk.u[1]) : "v"(p[2]), "v"(p[3]));
      asm("v_cvt_pk_bf16_f32 %0, %1, %2" : "=v"(pk.u[2]) : "v"(p[4]), "v"(p[5]));
      asm("v_cvt_pk_bf16_f32 %0, %1, %2" : "=v"(pk.u[3]) : "v"(p[6]), "v"(p[7]));
      pa[m] = pk.v8;
    }
    // PV
    __builtin_amdgcn_s_setprio(1);
    #pragma unroll
    for (int db = 0; db < 8; ++db) {
      o[0][db] = mfma16(pa[0], vf[db], o[0][db]);
      o[1][db] = mfma16(pa[1], vf[db], o[1][db]);
    }
    __builtin_amdgcn_s_setprio(0);
  };

#define WAIT6 asm volatile("s_waitcnt vmcnt(6)" ::: "memory")
#define WAIT0 asm volatile("s_waitcnt vmcnt(0)" ::: "memory")
#define BAR   __builtin_amdgcn_s_barrier()

  // prologue
  stage(Ks[0], Vs[0], 0);
  stage(Ks[1], Vs[1], KVB);
  WAIT6; BAR;
  // main: t = 0..59 in triples (all stages valid, all waits counted)
  int t = 0;
  for (int i = 0; i < 20; ++i) {
    stage(Ks[2], Vs[2], (t + 2) * KVB); compute(Ks[0], Vs[0]); WAIT6; BAR;
    stage(Ks[0], Vs[0], (t + 3) * KVB); compute(Ks[1], Vs[1]); WAIT6; BAR;
    stage(Ks[1], Vs[1], (t + 4) * KVB); compute(Ks[2], Vs[2]); WAIT6; BAR;
    t += 3;
  }
  // tail: t = 60..63
  stage(Ks[2], Vs[2], 62 * KVB); compute(Ks[0], Vs[0]); WAIT6; BAR;
  stage(Ks[0], Vs[0], 63 * KVB); compute(Ks[1], Vs[1]); WAIT6; BAR;
  compute(Ks[2], Vs[2]); WAIT0; BAR;
  compute(Ks[0], Vs[0]);

#undef WAIT6
#undef WAIT0
#undef BAR

  // deferred row-sum: lane holds partial for q=m*16+l15 over kv=lg-chunk
  #pragma unroll
  for (int m = 0; m < 2; ++m) {
    float l = l_part[m];
    l += __shfl_xor(l, 16);
    l += __shfl_xor(l, 32);            // full sum for q = m*16 + l15
    float inv[4];
    #pragma unroll
    for (int r = 0; r < 4; ++r)
      inv[r] = 1.0f / __shfl(l, lg * 4 + r);   // redistribute to o layout (q=lg*4+r)
    #pragma unroll
    for (int db = 0; db < 8; ++db)
      #pragma unroll
      for (int r = 0; r < 4; ++r) {
        int row = q0 + wid * 32 + m * 16 + lg * 4 + r;
        O[(size_t)(b * SEQ + row) * DIM + h * HEAD_DIM + db * 16 + l15] = f2bf(o[m][db][r] * inv[r]);
      }
  }
}

// ---------------- host ----------------
extern "C" void kernel_launch(void* const* d_in, const int* in_sizes, int n_in,
                              void* d_out, int out_size, void* d_ws, size_t ws_size,
                              hipStream_t stream) {
  const float* x     = (const float*)d_in[0];
  const float* wq_d  = (const float*)d_in[1];
  const float* wkv_d = (const float*)d_in[2];
  const float* wq_u  = (const float*)d_in[3];
  const float* wk_u  = (const float*)d_in[4];
  const float* wv_u  = (const float*)d_in[5];
  const float* wo    = (const float*)d_in[6];

  char* ws = (char*)d_ws;
  size_t off = 0;
  auto alloc = [&](size_t bytes) -> void* {
    void* p = ws + off;
    off += (bytes + 255) & ~(size_t)255;
    return p;
  };
  u16* wdT    = (u16*)alloc((size_t)512 * DIM * 2);
  u16* wquT   = (u16*)alloc((size_t)1024 * LATENT * 2);
  u16* wkuT   = (u16*)alloc((size_t)1024 * LATENT * 2);
  u16* wvuT   = (u16*)alloc((size_t)DIM * LATENT * 2);
  u16* woT    = (u16*)alloc((size_t)DIM * DIM * 2);
  u16* lat    = (u16*)alloc((size_t)TOK * 512 * 2);
  float* latP = (float*)alloc((size_t)4 * TOK * 512 * 4);   // split-K4 partials
  u16* qb     = (u16*)alloc((size_t)TOK * 1024 * 2);
  u16* kb     = (u16*)alloc((size_t)TOK * 1024 * 2);
  u16* vT     = (u16*)alloc((size_t)TOK * DIM * 2);
  u16* ao     = (u16*)alloc((size_t)TOK * DIM * 2);
  float* ct   = (float*)alloc((size_t)SEQ * 32 * 4);
  float* st   = (float*)alloc((size_t)SEQ * 32 * 4);
  (void)in_sizes; (void)n_in; (void)out_size; (void)ws_size;

  // fused prep: all weight transposes + rope tables in one launch
  prep_k<<<dim3(6400), dim3(32, 8), 0, stream>>>(wq_d, wkv_d, wq_u, wk_u, wv_u, wo,
                                                 wdT, wquT, wkuT, wvuT, woT, ct, st);

  // lat = x @ [wq_d|wkv_d]: MODE 5 reads fp32 x directly (reg-staged A,
  // in-flight bf16 convert — identical rounding to the old conv pass),
  // split-K4 -> fp32 partials -> bf16 combine
  gemm_bt<5><<<dim3(4, 32, 4), 256, 0, stream>>>((const u16*)x, DIM, 0, wdT, DIM, latP, TOK, 512, 512,
                                                 nullptr, nullptr, 0, nullptr, nullptr);
  combine_k<4, 0><<<(TOK * 512 / 4 + 255) / 256, 256, 0, stream>>>(latP, lat, TOK * 512 / 4, TOK * 512 / 4);

  // q,k up-proj merged (z: 0=q + RoPE + SCALE_C, 1=k + RoPE)
  gemm_bt<2><<<dim3(8, 32, 2), 256, 0, stream>>>(lat, 512, 0, wquT, LATENT, qb, TOK, 1024, LATENT,
                                                 wkuT, kb, 256, ct, st);
  // v up-proj with fused transposed+permuted vT write (MODE 4)
  gemm_bt<4><<<dim3(16, 32, 1), 256, 0, stream>>>(lat, 512, 256, wvuT, LATENT, vT, TOK, 2048, LATENT,
                                                  nullptr, nullptr, 0, nullptr, nullptr);

  attn_kernel<<<dim3(SEQ / 64, HEADS, BATCH), 128, 0, stream>>>(qb, kb, vT, ao);

  // out = attn_out @ wo — single GEMM, fp32 direct to d_out
  gemm_bt<3><<<dim3(16, 32, 1), 256, 0, stream>>>(ao, DIM, 0, woT, DIM, (float*)d_out, TOK, DIM, DIM,
                                                  nullptr, nullptr, 0, nullptr, nullptr);
}

// Round 13
// 178.905 us; speedup vs baseline: 1.1657x; 1.0384x over previous
//
#include <hip/hip_runtime.h>
#include <stdint.h>

typedef unsigned short u16;
typedef __attribute__((ext_vector_type(8))) short bf16x8;
typedef __attribute__((ext_vector_type(4))) float f32x4;
typedef __attribute__((ext_vector_type(4))) unsigned short u16x4;

#define DIM 2048
#define HEADS 16
#define HEAD_DIM 128
#define HALF 64
#define LATENT 256
#define BATCH 2
#define SEQ 2048
#define TOK (BATCH*SEQ)

#if defined(__has_builtin)
#if __has_builtin(__builtin_amdgcn_exp2f)
#define EXP2F(x) __builtin_amdgcn_exp2f(x)
#endif
#endif
#ifndef EXP2F
#define EXP2F(x) exp2f(x)
#endif

#define SCALE_C 0.18033688011112042f   // (1/sqrt(64)) * log2(e), folded into Q

__device__ __forceinline__ u16 f2bf(float f) {
  uint32_t u = __float_as_uint(f);
  u += 0x7fff + ((u >> 16) & 1);   // round-to-nearest-even
  return (u16)(u >> 16);
}

__device__ __forceinline__ f32x4 mfma16(bf16x8 a, bf16x8 b, f32x4 c) {
  return __builtin_amdgcn_mfma_f32_16x16x32_bf16(a, b, c, 0, 0, 0);
}

__device__ __forceinline__ void async_copy16(const void* g, void* l) {
  __builtin_amdgcn_global_load_lds(
      (const __attribute__((address_space(1))) void*)g,
      (__attribute__((address_space(3))) void*)l, 16, 0, 0);
}

// ---------------- fused prep: 4 weight transposes + rope tables ----------------
__global__ void prep_k(const float* __restrict__ wq_d, const float* __restrict__ wkv_d,
                       const float* __restrict__ wq_u, const float* __restrict__ wk_u,
                       const float* __restrict__ wv_u, const float* __restrict__ wo,
                       u16* __restrict__ wdT, u16* __restrict__ wquT, u16* __restrict__ wkuT,
                       u16* __restrict__ wvuT, u16* __restrict__ woT,
                       float* __restrict__ ct, float* __restrict__ st) {
  __shared__ float tile[32][33];
  const int f = blockIdx.x;
  const int tx = threadIdx.x, ty = threadIdx.y;

  const float* in = nullptr;
  u16* out = nullptr;
  int N = 0, row_off = 0, out_ld = 0, bx = 0, by = 0;

  if (f < 1024) {
    int z = f >> 9, r = f & 511;
    bx = r & 7; by = r >> 3;
    in = z ? wkv_d : wq_d; out = wdT; row_off = z * 256; N = 256; out_ld = 2048;
  } else if (f < 1536) {
    int r = f - 1024; int z = r >> 8; r &= 255;
    bx = r & 31; by = r >> 5;
    in = z ? wk_u : wq_u; out = z ? wkuT : wquT; row_off = 0; N = 1024; out_ld = 256;
  } else if (f < 2048) {
    int r = f - 1536;
    bx = r & 63; by = r >> 6;
    in = wv_u; out = wvuT; row_off = 0; N = 2048; out_ld = 256;
  } else if (f < 6144) {
    int r = f - 2048;
    bx = r & 63; by = r >> 6;
    in = wo; out = woT; row_off = 0; N = 2048; out_ld = 2048;
  } else {
    int t = (f - 6144) * 256 + ty * 32 + tx;
    int i = t & 31, s = t >> 5;
    float invf = expf(-(float)i * 0.28782313662425575f);
    float a = (float)s * invf;
    ct[t] = cosf(a);
    st[t] = sinf(a);
    return;
  }
  int k0 = by * 32, n0 = bx * 32;
  #pragma unroll
  for (int j = 0; j < 32; j += 8)
    tile[ty + j][tx] = in[(size_t)(k0 + ty + j) * N + n0 + tx];
  __syncthreads();
  #pragma unroll
  for (int j = 0; j < 32; j += 8)
    out[(size_t)(n0 + ty + j + row_off) * out_ld + k0 + tx] = f2bf(tile[tx][ty + j]);
}

// ---------------- combine split-K partials ----------------
template<int NS, int OUTF32>
__global__ void combine_k(const float* __restrict__ p, void* __restrict__ out, int n4, int slab4) {
  int t = blockIdx.x * 256 + threadIdx.x;
  if (t >= n4) return;
  float4 a = ((const float4*)p)[t];
  #pragma unroll
  for (int s = 1; s < NS; ++s) {
    float4 b = ((const float4*)p)[t + (size_t)s * slab4];
    a.x += b.x; a.y += b.y; a.z += b.z; a.w += b.w;
  }
  if (OUTF32) ((float4*)out)[t] = a;
  else { u16x4 o = { f2bf(a.x), f2bf(a.y), f2bf(a.z), f2bf(a.w) };
         *(u16x4*)((u16*)out + (size_t)t * 4) = o; }
}

// ---------------- GEMM: C[M][N] = A[M][K] @ BT[N][K]^T ----------------
// MODE 3: split-K; z = K-slab index; f32 out to Cv + z*M*N (K = slab size).
// MODE 5: like MODE 3 but A is fp32 (reg-staged with in-flight bf16 convert).
template<int MODE>
__global__ __launch_bounds__(256)
void gemm_bt(const u16* __restrict__ A, int lda, int a_off,
             const u16* __restrict__ BT, int ldb,
             void* __restrict__ Cv, int M, int N, int K) {
  __shared__ __align__(16) u16 As[128 * 32];
  __shared__ __align__(16) u16 Bs[128 * 32];
  const int tid = threadIdx.x;
  const int lane = tid & 63;
  const int wid = tid >> 6;
  const int z = blockIdx.z;
  int koff = z * K;
  // XCD swizzle within the x-y plane (all grids are multiples of 8)
  const int nb = gridDim.x * gridDim.y;
  int f = blockIdx.x + gridDim.x * blockIdx.y;
  f = (f & 7) * (nb >> 3) + (f >> 3);
  const int m0 = (f / gridDim.x) * 128;
  const int n0 = (f % gridDim.x) * 128;
  const int wr = wid >> 1, wc = wid & 1;
  const int l15 = lane & 15, lg = lane >> 4;
  const int rA = lane >> 2;
  const int kq = (lane & 3) * 8;

  f32x4 acc[4][4] = {};
  const int nk = K / 32;
  for (int kt = 0; kt < nk; ++kt) {
    const int k0 = koff + kt * 32;
    #pragma unroll
    for (int c = 0; c < 2; ++c) {
      int ca = wid * 2 + c;
      if (MODE == 5) {
        const float* Af = (const float*)A;
        const float* ga = Af + (size_t)(m0 + ca * 16 + rA) * lda + a_off + k0 + kq;
        float4 v0 = *(const float4*)ga;
        float4 v1 = *(const float4*)(ga + 4);
        union { u16 h[8]; bf16x8 v; } pk;
        pk.h[0] = f2bf(v0.x); pk.h[1] = f2bf(v0.y); pk.h[2] = f2bf(v0.z); pk.h[3] = f2bf(v0.w);
        pk.h[4] = f2bf(v1.x); pk.h[5] = f2bf(v1.y); pk.h[6] = f2bf(v1.z); pk.h[7] = f2bf(v1.w);
        *(bf16x8*)&As[ca * 512 + rA * 32 + kq] = pk.v;
      } else {
        const u16* ga = A + (size_t)(m0 + ca * 16 + rA) * lda + a_off + k0 + kq;
        async_copy16(ga, &As[ca * 512]);
      }
      const u16* gb = BT + (size_t)(n0 + ca * 16 + rA) * ldb + k0 + kq;
      async_copy16(gb, &Bs[ca * 512]);
    }
    __syncthreads();
    bf16x8 af[4], bfr[4];
    #pragma unroll
    for (int i = 0; i < 4; ++i) {
      af[i]  = *(const bf16x8*)&As[(wr * 64 + i * 16 + l15) * 32 + lg * 8];
      bfr[i] = *(const bf16x8*)&Bs[(wc * 64 + i * 16 + l15) * 32 + lg * 8];
    }
    #pragma unroll
    for (int i = 0; i < 4; ++i)
      #pragma unroll
      for (int j = 0; j < 4; ++j)
        acc[i][j] = mfma16(af[i], bfr[j], acc[i][j]);
    __syncthreads();
  }
  #pragma unroll
  for (int i = 0; i < 4; ++i) {
    #pragma unroll
    for (int j = 0; j < 4; ++j) {
      int row = m0 + wr * 64 + i * 16 + lg * 4;
      int col = n0 + wc * 64 + j * 16 + l15;
      #pragma unroll
      for (int r = 0; r < 4; ++r)
        ((float*)Cv)[(size_t)z * M * N + (size_t)(row + r) * N + col] = acc[i][j][r];
    }
  }
}

// ---------------- merged up-proj: q (RoPE+scale), k (RoPE), v (transposed vT) ----------------
// ONE flat 1024-block launch (4 blocks/CU). XCD swizzle first (each XCD gets a
// contiguous 128-id chunk), then segment decode:
//   [0,256):   q  = lat[:, 0:256]   @ wquT -> qb, RoPE * SCALE_C   (grid 8x32)
//   [256,512): k  = lat[:, 256:512] @ wkuT -> kb, RoPE             (grid 8x32)
//   [512,1024):v  = lat[:, 256:512] @ wvuT -> vT[b][c][p(s)]       (grid 16x32)
__global__ __launch_bounds__(256)
void upproj_k(const u16* __restrict__ A,
              const u16* __restrict__ wquT, const u16* __restrict__ wkuT,
              const u16* __restrict__ wvuT,
              u16* __restrict__ qb, u16* __restrict__ kb, u16* __restrict__ vT,
              const float* __restrict__ ct, const float* __restrict__ st) {
  __shared__ __align__(16) u16 As[128 * 32];
  __shared__ __align__(16) u16 Bs[128 * 32];
  const int tid = threadIdx.x;
  const int lane = tid & 63;
  const int wid = tid >> 6;
  int f = blockIdx.x;
  f = (f & 7) * 128 + (f >> 3);          // XCD swizzle over flat 1024
  const u16* BT; u16* out; int N, a_off, seg, r;
  if (f < 256)      { seg = 0; r = f;       BT = wquT; out = qb; N = 1024; a_off = 0; }
  else if (f < 512) { seg = 1; r = f - 256; BT = wkuT; out = kb; N = 1024; a_off = 256; }
  else              { seg = 2; r = f - 512; BT = wvuT; out = vT; N = 2048; a_off = 256; }
  const int gx = (seg == 2) ? 16 : 8;
  const int m0 = (r / gx) * 128;
  const int n0 = (r % gx) * 128;
  const int wr = wid >> 1, wc = wid & 1;
  const int l15 = lane & 15, lg = lane >> 4;
  const int rA = lane >> 2;
  const int kq = (lane & 3) * 8;

  f32x4 acc[4][4] = {};
  for (int kt = 0; kt < LATENT / 32; ++kt) {
    const int k0 = kt * 32;
    #pragma unroll
    for (int c = 0; c < 2; ++c) {
      int ca = wid * 2 + c;
      async_copy16(A + (size_t)(m0 + ca * 16 + rA) * 512 + a_off + k0 + kq, &As[ca * 512]);
      async_copy16(BT + (size_t)(n0 + ca * 16 + rA) * LATENT + k0 + kq, &Bs[ca * 512]);
    }
    __syncthreads();
    bf16x8 af[4], bfr[4];
    #pragma unroll
    for (int i = 0; i < 4; ++i) {
      af[i]  = *(const bf16x8*)&As[(wr * 64 + i * 16 + l15) * 32 + lg * 8];
      bfr[i] = *(const bf16x8*)&Bs[(wc * 64 + i * 16 + l15) * 32 + lg * 8];
    }
    #pragma unroll
    for (int i = 0; i < 4; ++i)
      #pragma unroll
      for (int j = 0; j < 4; ++j)
        acc[i][j] = mfma16(af[i], bfr[j], acc[i][j]);
    __syncthreads();
  }

  if (seg <= 1) {
    // fused RoPE epilogue; q (seg==0) additionally scaled by SCALE_C
    const float qs = seg ? 1.0f : SCALE_C;
    #pragma unroll
    for (int i = 0; i < 4; ++i) {
      int rowb = m0 + wr * 64 + i * 16 + lg * 4;
      #pragma unroll
      for (int j = 0; j < 2; ++j) {
        int ii = j * 16 + l15;                 // 0..31 within head
        int colb = n0 + wc * 64;
        #pragma unroll
        for (int r2 = 0; r2 < 4; ++r2) {
          int s = (rowb + r2) & (SEQ - 1);
          float c = ct[s * 32 + ii], sn = st[s * 32 + ii];
          float x1 = acc[i][j][r2], x2 = acc[i][j + 2][r2];
          out[(size_t)(rowb + r2) * N + colb + ii]      = f2bf((x1 * c - x2 * sn) * qs);
          out[(size_t)(rowb + r2) * N + colb + ii + 32] = f2bf((x2 * c + x1 * sn) * qs);
        }
      }
    }
  } else {
    // transposed+permuted write: vT[b][c][p(s)], p(s) consecutive over r
    const int bb = m0 >> 11;                   // batch (tile never straddles)
    #pragma unroll
    for (int i = 0; i < 4; ++i) {
      int rowb = m0 + wr * 64 + i * 16 + lg * 4;   // token, ≡0 mod 4
      int s = rowb & (SEQ - 1);
      int pbase = (s & ~31) + (((s & 15) >> 2) << 3) + (((s >> 4) & 1) << 2);
      #pragma unroll
      for (int j = 0; j < 4; ++j) {
        int c = n0 + wc * 64 + j * 16 + l15;
        u16x4 ov = { f2bf(acc[i][j][0]), f2bf(acc[i][j][1]),
                     f2bf(acc[i][j][2]), f2bf(acc[i][j][3]) };
        *(u16x4*)&out[(size_t)bb * SEQ * DIM + (size_t)c * SEQ + pbase] = ov;
      }
    }
  }
}

// ---------------- flash attention v9 (best measured config, frozen) ----------------
#define KVB 32
__global__ __launch_bounds__(128, 2)
void attn_kernel(const u16* __restrict__ Q, const u16* __restrict__ Kb,
                 const u16* __restrict__ VT, u16* __restrict__ O) {
  __shared__ __align__(16) u16 Ks[3][KVB * 64];        // 4KB/buf
  __shared__ __align__(16) u16 Vs[3][HEAD_DIM * KVB];  // 8KB/buf

  const int tid = threadIdx.x, lane = tid & 63, wid = tid >> 6;
  int fl = blockIdx.x + 32 * (blockIdx.y + 16 * blockIdx.z);
  fl = (fl & 7) * 128 + (fl >> 3);
  const int q0 = (fl & 31) * 64;
  const int h = (fl >> 5) & 15;
  const int b = fl >> 9;
  const int l15 = lane & 15, lg = lane >> 4;

  const u16* kbp = Kb + (size_t)(b * SEQ) * (HEADS * HALF) + h * HALF;
  const u16* vtb = VT + (size_t)b * SEQ * DIM + (size_t)(h * HEAD_DIM) * SEQ;

  bf16x8 qf[2][2];
  #pragma unroll
  for (int m = 0; m < 2; ++m)
    #pragma unroll
    for (int ks = 0; ks < 2; ++ks)
      qf[m][ks] = *(const bf16x8*)&Q[(size_t)(b * SEQ + q0 + wid * 32 + m * 16 + l15) * (HEADS * HALF)
                                     + h * HALF + ks * 32 + lg * 8];

  f32x4 o[2][8] = {};
  float l_part[2] = {0.f, 0.f};

  const int kRow = lane >> 3;
  const int kColB = ((lane & 7) ^ kRow) * 16;
  const int vRow = lane >> 2;
  const int vColB = ((lane & 3) ^ ((lane >> 3) & 3)) * 16;

  auto stage = [&](u16* KsD, u16* VsD, int kv0) {
    #pragma unroll
    for (int i = 0; i < 2; ++i) {
      int c = wid * 2 + i;
      const u16* src = kbp + (size_t)(kv0 + c * 8 + kRow) * (HEADS * HALF) + (kColB >> 1);
      async_copy16(src, KsD + c * 512);
    }
    #pragma unroll
    for (int i = 0; i < 4; ++i) {
      int c = wid * 4 + i;
      const u16* src = vtb + (size_t)(c * 16 + vRow) * SEQ + kv0 + (vColB >> 1);
      async_copy16(src, VsD + c * 512);
    }
  };

  auto compute = [&](const u16* KsP, const u16* VsP) {
    const char* KsB = (const char*)KsP;
    const char* VsB = (const char*)VsP;
    const int kswz = (l15 & 7) << 4;
    bf16x8 kf[2][2], vf[8];
    #pragma unroll
    for (int ks = 0; ks < 2; ++ks)
      #pragma unroll
      for (int nf = 0; nf < 2; ++nf)
        kf[ks][nf] = *(const bf16x8*)(KsB + (nf * 16 + l15) * 128 + ((ks * 64 + lg * 16) ^ kswz));
    #pragma unroll
    for (int db = 0; db < 8; ++db) {
      int row = db * 16 + l15;
      vf[db] = *(const bf16x8*)(VsB + row * 64 + ((lg * 16) ^ (((row >> 1) & 3) << 4)));
    }
    f32x4 s[2][2] = {};
    __builtin_amdgcn_s_setprio(1);
    #pragma unroll
    for (int ks = 0; ks < 2; ++ks)
      #pragma unroll
      for (int nf = 0; nf < 2; ++nf) {
        s[0][nf] = mfma16(kf[ks][nf], qf[0][ks], s[0][nf]);
        s[1][nf] = mfma16(kf[ks][nf], qf[1][ks], s[1][nf]);
      }
    __builtin_amdgcn_s_setprio(0);
    bf16x8 pa[2];
    #pragma unroll
    for (int m = 0; m < 2; ++m) {
      float p[8];
      #pragma unroll
      for (int nf = 0; nf < 2; ++nf)
        #pragma unroll
        for (int r = 0; r < 4; ++r) {
          float v = EXP2F(s[m][nf][r]);
          p[nf * 4 + r] = v;
          l_part[m] += v;
        }
      union { uint32_t u[4]; bf16x8 v8; } pk;
      asm("v_cvt_pk_bf16_f32 %0, %1, %2" : "=v"(pk.u[0]) : "v"(p[0]), "v"(p[1]));
      asm("v_cvt_pk_bf16_f32 %0, %1, %2" : "=v"(pk.u[1]) : "v"(p[2]), "v"(p[3]));
      asm("v_cvt_pk_bf16_f32 %0, %1, %2" : "=v"(pk.u[2]) : "v"(p[4]), "v"(p[5]));
      asm("v_cvt_pk_bf16_f32 %0, %1, %2" : "=v"(pk.u[3]) : "v"(p[6]), "v"(p[7]));
      pa[m] = pk.v8;
    }
    __builtin_amdgcn_s_setprio(1);
    #pragma unroll
    for (int db = 0; db < 8; ++db) {
      o[0][db] = mfma16(pa[0], vf[db], o[0][db]);
      o[1][db] = mfma16(pa[1], vf[db], o[1][db]);
    }
    __builtin_amdgcn_s_setprio(0);
  };

#define WAIT6 asm volatile("s_waitcnt vmcnt(6)" ::: "memory")
#define WAIT0 asm volatile("s_waitcnt vmcnt(0)" ::: "memory")
#define BAR   __builtin_amdgcn_s_barrier()

  stage(Ks[0], Vs[0], 0);
  stage(Ks[1], Vs[1], KVB);
  WAIT6; BAR;
  int t = 0;
  for (int i = 0; i < 20; ++i) {
    stage(Ks[2], Vs[2], (t + 2) * KVB); compute(Ks[0], Vs[0]); WAIT6; BAR;
    stage(Ks[0], Vs[0], (t + 3) * KVB); compute(Ks[1], Vs[1]); WAIT6; BAR;
    stage(Ks[1], Vs[1], (t + 4) * KVB); compute(Ks[2], Vs[2]); WAIT6; BAR;
    t += 3;
  }
  stage(Ks[2], Vs[2], 62 * KVB); compute(Ks[0], Vs[0]); WAIT6; BAR;
  stage(Ks[0], Vs[0], 63 * KVB); compute(Ks[1], Vs[1]); WAIT6; BAR;
  compute(Ks[2], Vs[2]); WAIT0; BAR;
  compute(Ks[0], Vs[0]);

#undef WAIT6
#undef WAIT0
#undef BAR

  #pragma unroll
  for (int m = 0; m < 2; ++m) {
    float l = l_part[m];
    l += __shfl_xor(l, 16);
    l += __shfl_xor(l, 32);
    float inv[4];
    #pragma unroll
    for (int r = 0; r < 4; ++r)
      inv[r] = 1.0f / __shfl(l, lg * 4 + r);
    #pragma unroll
    for (int db = 0; db < 8; ++db)
      #pragma unroll
      for (int r = 0; r < 4; ++r) {
        int row = q0 + wid * 32 + m * 16 + lg * 4 + r;
        O[(size_t)(b * SEQ + row) * DIM + h * HEAD_DIM + db * 16 + l15] = f2bf(o[m][db][r] * inv[r]);
      }
  }
}

// ---------------- host ----------------
extern "C" void kernel_launch(void* const* d_in, const int* in_sizes, int n_in,
                              void* d_out, int out_size, void* d_ws, size_t ws_size,
                              hipStream_t stream) {
  const float* x     = (const float*)d_in[0];
  const float* wq_d  = (const float*)d_in[1];
  const float* wkv_d = (const float*)d_in[2];
  const float* wq_u  = (const float*)d_in[3];
  const float* wk_u  = (const float*)d_in[4];
  const float* wv_u  = (const float*)d_in[5];
  const float* wo    = (const float*)d_in[6];

  char* ws = (char*)d_ws;
  size_t off = 0;
  auto alloc = [&](size_t bytes) -> void* {
    void* p = ws + off;
    off += (bytes + 255) & ~(size_t)255;
    return p;
  };
  u16* wdT    = (u16*)alloc((size_t)512 * DIM * 2);
  u16* wquT   = (u16*)alloc((size_t)1024 * LATENT * 2);
  u16* wkuT   = (u16*)alloc((size_t)1024 * LATENT * 2);
  u16* wvuT   = (u16*)alloc((size_t)DIM * LATENT * 2);
  u16* woT    = (u16*)alloc((size_t)DIM * DIM * 2);
  u16* lat    = (u16*)alloc((size_t)TOK * 512 * 2);
  float* latP = (float*)alloc((size_t)4 * TOK * 512 * 4);   // split-K4 partials
  u16* qb     = (u16*)alloc((size_t)TOK * 1024 * 2);
  u16* kb     = (u16*)alloc((size_t)TOK * 1024 * 2);
  u16* vT     = (u16*)alloc((size_t)TOK * DIM * 2);
  u16* ao     = (u16*)alloc((size_t)TOK * DIM * 2);
  float* ct   = (float*)alloc((size_t)SEQ * 32 * 4);
  float* st   = (float*)alloc((size_t)SEQ * 32 * 4);
  (void)in_sizes; (void)n_in; (void)out_size; (void)ws_size;

  // fused prep: all weight transposes + rope tables in one launch
  prep_k<<<dim3(6400), dim3(32, 8), 0, stream>>>(wq_d, wkv_d, wq_u, wk_u, wv_u, wo,
                                                 wdT, wquT, wkuT, wvuT, woT, ct, st);

  // lat = x @ [wq_d|wkv_d]: MODE 5 reads fp32 x directly, split-K4 -> combine
  gemm_bt<5><<<dim3(4, 32, 4), 256, 0, stream>>>((const u16*)x, DIM, 0, wdT, DIM, latP, TOK, 512, 512);
  combine_k<4, 0><<<(TOK * 512 / 4 + 255) / 256, 256, 0, stream>>>(latP, lat, TOK * 512 / 4, TOK * 512 / 4);

  // merged q/k/v up-proj: one 1024-block launch (RoPE+scale, RoPE, vT scatter)
  upproj_k<<<dim3(1024), 256, 0, stream>>>(lat, wquT, wkuT, wvuT, qb, kb, vT, ct, st);

  attn_kernel<<<dim3(SEQ / 64, HEADS, BATCH), 128, 0, stream>>>(qb, kb, vT, ao);

  // out = attn_out @ wo — single GEMM, fp32 direct to d_out
  gemm_bt<3><<<dim3(16, 32, 1), 256, 0, stream>>>(ao, DIM, 0, woT, DIM, (float*)d_out, TOK, DIM, DIM);
}